// Round 10
// baseline (265.635 us; speedup 1.0000x reference)
//
#include <hip/hip_runtime.h>
#include <math.h>

// ConvCaps: A=B=32, C=D=16, K=3, stride=2, ITERS=3
// pose: [4][512][32][32] f32, W: [288][512][16] f32, out: [4][512][15][15] f32
// pos = batch*225 + oi*15 + oj  (900 valid, padded to 928 = 29 tiles of 32)
#define KC   18      // k-chunks (parallelism axis)
#define KPC  16      // k per chunk (18*16 = 288)
#define NP   928
#define NPT  29

typedef __attribute__((ext_vector_type(8)))  short short8;   // 8 bf16 = 4 VGPR
typedef __attribute__((ext_vector_type(16))) float f32x16;   // MFMA C/D

__device__ __forceinline__ unsigned short f2bf(float x) {
    union { float f; unsigned u; } v; v.f = x;
    unsigned r = v.u + 0x7fffu + ((v.u >> 16) & 1u);
    return (unsigned short)(r >> 16);
}
__device__ __forceinline__ float bf2f(unsigned short h) {
    union { unsigned u; float f; } v; v.u = ((unsigned)h) << 16;
    return v.f;
}

// ---------------- W -> split bf16 (hi, lo) ----------------
__global__ void wprep(const float* __restrict__ W,
                      unsigned short* __restrict__ Whi,
                      unsigned short* __restrict__ Wlo)
{
    int idx = (blockIdx.x * 256 + threadIdx.x) * 4;
    float4 x = *(const float4*)(W + idx);
    ushort4 h, l;
    h.x = f2bf(x.x); l.x = f2bf(x.x - bf2f(h.x));
    h.y = f2bf(x.y); l.y = f2bf(x.y - bf2f(h.y));
    h.z = f2bf(x.z); l.z = f2bf(x.z - bf2f(h.z));
    h.w = f2bf(x.w); l.w = f2bf(x.w - bf2f(h.w));
    *(ushort4*)(Whi + idx) = h;
    *(ushort4*)(Wlo + idx) = l;
}

// ---------------- unfold pose -> split bf16 P[k][pos(928)][c(16)] ----------------
// block = (batch, a); stage 16 pose planes in LDS (row stride 33, plane 1057),
// then emit all 9 kernel-offset copies coalesced.
__global__ __launch_bounds__(256) void unfold(const float* __restrict__ pose,
                                              unsigned short* __restrict__ Phi,
                                              unsigned short* __restrict__ Plo)
{
    __shared__ float lds[16 * 1057];
    const int bid = blockIdx.x;          // 128 = 4 batch * 32 a
    const int batch = bid >> 5;
    const int a = bid & 31;
    const int t = threadIdx.x;

    const float* src = pose + ((size_t)batch * 512 + a * 16) * 1024;
#pragma unroll
    for (int c = 0; c < 16; ++c) {
        float4 v = *(const float4*)(src + c * 1024 + t * 4);
        float* d = &lds[c * 1057 + (t >> 3) * 33 + (t & 7) * 4];
        d[0] = v.x; d[1] = v.y; d[2] = v.z; d[3] = v.w;
    }
    __syncthreads();

    const int c = t & 15;
    const int px = t >> 4;
    for (int it = 0; it < 15; ++it) {
        int pos = it * 16 + px;
        bool ok = pos < 225;
        int pc = ok ? pos : 224;
        int oi = pc / 15, oj = pc - oi * 15;
#pragma unroll
        for (int ki = 0; ki < 3; ++ki)
#pragma unroll
            for (int kj = 0; kj < 3; ++kj) {
                float val = lds[c * 1057 + (oi * 2 + ki) * 33 + (oj * 2 + kj)];
                unsigned short hh = f2bf(val);
                unsigned short ll = f2bf(val - bf2f(hh));
                if (ok) {
                    size_t o = ((size_t)((ki * 3 + kj) * 32 + a) * NP
                                + batch * 225 + pos) * 16 + c;
                    Phi[o] = hh;
                    Plo[o] = ll;
                }
            }
    }
}

// ---------------- routing pass ----------------
// grid = 18 k-chunks (major) * 29 pos-tiles, block 512 = 8 waves.
// Swapped MFMA: D[bd(32-tile)][pos(32)] = W_k[bd][c] * p^T[c][pos], 32x32x16 bf16.
//   A frag: row = lane&31 (bd), c = (lane>>5)*8 + j
//   B frag: col = lane&31 (pos), c = (lane>>5)*8 + j
//   C/D  : col = lane&31 (pos), row(bd) = (reg&3) + 8*(reg>>2) + 4*(lane>>5)
// Wave w owns bd in [w*64, w*64+64).
// T14 async-STAGE: per k-step, stage next W_k slab (32 KB hi+lo) + P slab (2 KB)
// global->reg at step top, ds_write at step bottom; double-buffered LDS; ONE
// lgkmcnt-only barrier per step. This maximizes bytes-in-flight (the round-9
// bottleneck: 400 KB in flight == 1.06 TB/s fetch ceiling, measured).
template<int ITER>
__global__ __launch_bounds__(512, 2) void route(const unsigned short* __restrict__ Whi,
                                                const unsigned short* __restrict__ Wlo,
                                                const unsigned short* __restrict__ Phi,
                                                const unsigned short* __restrict__ Plo,
                                                const float* __restrict__ V,
                                                unsigned short* __restrict__ part)
{
    __shared__ __align__(16) unsigned short wlds[2][16384]; // [buf][hi 8192 | lo 8192] shorts
    __shared__ __align__(16) unsigned short plds[2][1024];  // [buf][hi 512 | lo 512] shorts
    __shared__ float2 smb[2][8][32];   // [buf][wave][pos]: (wave max, wave expsum)

    const int bid = blockIdx.x;
    const int pt = bid % NPT;          // kc-major: consecutive bids share W chunk
    const int kc = bid / NPT;
    const int t = threadIdx.x;
    const int w = t >> 6;
    const int l = t & 63;
    const int col = l & 31;            // pos within tile
    const int h = l >> 5;
    const int gpos = pt * 32 + col;
    const int bd0 = w * 64;
    const int k0 = kc * KPC;

    float vf[2][16];
    if constexpr (ITER > 0) {
        const float* vp = V + (size_t)gpos * 512 + bd0 + 4 * h;
#pragma unroll
        for (int m = 0; m < 2; ++m)
#pragma unroll
            for (int q = 0; q < 4; ++q) {
                float4 x = *(const float4*)(vp + m * 32 + 8 * q);
                vf[m][q * 4 + 0] = x.x; vf[m][q * 4 + 1] = x.y;
                vf[m][q * 4 + 2] = x.z; vf[m][q * 4 + 3] = x.w;
            }
    }

    f32x16 s[2];
#pragma unroll
    for (int m = 0; m < 2; ++m)
#pragma unroll
        for (int r = 0; r < 16; ++r) s[m][r] = 0.f;

    // P staged by waves 0 (hi) / 1 (lo); other waves load same addrs (dup, dead)
    const unsigned short* gP = (w & 1) ? Plo : Phi;

    // prologue: stage k0 into buf 0
    {
        const size_t wb = (size_t)k0 * 8192;
        const size_t pb = ((size_t)k0 * NP + pt * 32) * 16;
        short8 r0 = *(const short8*)(Whi + wb + t * 8);
        short8 r1 = *(const short8*)(Whi + wb + 4096 + t * 8);
        short8 r2 = *(const short8*)(Wlo + wb + t * 8);
        short8 r3 = *(const short8*)(Wlo + wb + 4096 + t * 8);
        short8 rp = *(const short8*)(gP + pb + l * 8);
        *(short8*)&wlds[0][t * 8]          = r0;
        *(short8*)&wlds[0][4096 + t * 8]   = r1;
        *(short8*)&wlds[0][8192 + t * 8]   = r2;
        *(short8*)&wlds[0][12288 + t * 8]  = r3;
        if (w < 2) *(short8*)&plds[0][w * 512 + l * 8] = rp;
    }
    __syncthreads();

    for (int kl = 0; kl < KPC; ++kl) {
        const int cb = kl & 1, nb = cb ^ 1;

        // (1) issue next-step staging loads (latency hides under this step)
        //     last step reads one slab past k-range — lands in the next ws
        //     region (Whi->Wlo->Phi->Plo->part), in-bounds, values unused.
        const size_t wb = (size_t)(k0 + kl + 1) * 8192;
        const size_t pb = ((size_t)(k0 + kl + 1) * NP + pt * 32) * 16;
        short8 r0 = *(const short8*)(Whi + wb + t * 8);
        short8 r1 = *(const short8*)(Whi + wb + 4096 + t * 8);
        short8 r2 = *(const short8*)(Wlo + wb + t * 8);
        short8 r3 = *(const short8*)(Wlo + wb + 4096 + t * 8);
        short8 rp = *(const short8*)(gP + pb + l * 8);

        // (2) frag reads from LDS (buf cb)
        const int wa = (bd0 + col) * 16 + 8 * h;
        const int pa = col * 16 + 8 * h;
        short8 ah0 = *(const short8*)&wlds[cb][wa];
        short8 ah1 = *(const short8*)&wlds[cb][wa + 512];
        short8 al0 = *(const short8*)&wlds[cb][8192 + wa];
        short8 al1 = *(const short8*)&wlds[cb][8192 + wa + 512];
        short8 bh  = *(const short8*)&plds[cb][pa];
        short8 bl  = *(const short8*)&plds[cb][512 + pa];

        if constexpr (ITER == 0) {
            s[0] = __builtin_amdgcn_mfma_f32_32x32x16_bf16(ah0, bh, s[0], 0, 0, 0);
            s[1] = __builtin_amdgcn_mfma_f32_32x32x16_bf16(ah1, bh, s[1], 0, 0, 0);
            s[0] = __builtin_amdgcn_mfma_f32_32x32x16_bf16(ah0, bl, s[0], 0, 0, 0);
            s[1] = __builtin_amdgcn_mfma_f32_32x32x16_bf16(ah1, bl, s[1], 0, 0, 0);
            s[0] = __builtin_amdgcn_mfma_f32_32x32x16_bf16(al0, bh, s[0], 0, 0, 0);
            s[1] = __builtin_amdgcn_mfma_f32_32x32x16_bf16(al1, bh, s[1], 0, 0, 0);

            // (4) ds_write staged regs -> buf nb (compiler waits vmcnt first)
            *(short8*)&wlds[nb][t * 8]         = r0;
            *(short8*)&wlds[nb][4096 + t * 8]  = r1;
            *(short8*)&wlds[nb][8192 + t * 8]  = r2;
            *(short8*)&wlds[nb][12288 + t * 8] = r3;
            if (w < 2) *(short8*)&plds[nb][w * 512 + l * 8] = rp;
            // (5) drain LDS ops, barrier: next buf ready, cur buf free
            asm volatile("s_waitcnt lgkmcnt(0)\n\ts_barrier" ::: "memory");
        } else {
            f32x16 v[2];
#pragma unroll
            for (int m = 0; m < 2; ++m)
#pragma unroll
                for (int r = 0; r < 16; ++r) v[m][r] = 0.f;
            v[0] = __builtin_amdgcn_mfma_f32_32x32x16_bf16(ah0, bh, v[0], 0, 0, 0);
            v[1] = __builtin_amdgcn_mfma_f32_32x32x16_bf16(ah1, bh, v[1], 0, 0, 0);
            v[0] = __builtin_amdgcn_mfma_f32_32x32x16_bf16(ah0, bl, v[0], 0, 0, 0);
            v[1] = __builtin_amdgcn_mfma_f32_32x32x16_bf16(ah1, bl, v[1], 0, 0, 0);
            v[0] = __builtin_amdgcn_mfma_f32_32x32x16_bf16(al0, bh, v[0], 0, 0, 0);
            v[1] = __builtin_amdgcn_mfma_f32_32x32x16_bf16(al1, bh, v[1], 0, 0, 0);

            // logits[pos, b] = votes . V ;  b = w*4 + (m*2 + (q>>1))
            float lp[4] = {0.f, 0.f, 0.f, 0.f};
#pragma unroll
            for (int m = 0; m < 2; ++m)
#pragma unroll
                for (int q = 0; q < 4; ++q)
#pragma unroll
                    for (int i = 0; i < 4; ++i)
                        lp[m * 2 + (q >> 1)] = fmaf(v[m][q * 4 + i], vf[m][q * 4 + i],
                                                    lp[m * 2 + (q >> 1)]);
#pragma unroll
            for (int j = 0; j < 4; ++j) lp[j] += __shfl_xor(lp[j], 32);

            // wave-local softmax partial over this wave's 4 b's
            float mw = fmaxf(fmaxf(lp[0], lp[1]), fmaxf(lp[2], lp[3]));
            float ex[4], sw = 0.f;
#pragma unroll
            for (int j = 0; j < 4; ++j) { ex[j] = __expf(lp[j] - mw); sw += ex[j]; }
            if (h == 0) smb[cb][w][col] = make_float2(mw, sw);

            // (4) ds_write staged regs -> buf nb
            *(short8*)&wlds[nb][t * 8]         = r0;
            *(short8*)&wlds[nb][4096 + t * 8]  = r1;
            *(short8*)&wlds[nb][8192 + t * 8]  = r2;
            *(short8*)&wlds[nb][12288 + t * 8] = r3;
            if (w < 2) *(short8*)&plds[nb][w * 512 + l * 8] = rp;
            // (5) drain LDS ops (smb write + staging writes + frag reads), barrier
            asm volatile("s_waitcnt lgkmcnt(0)\n\ts_barrier" ::: "memory");

            // (6) combine 8 wave partials -> softmax weights; accumulate s
            float2 z[8];
            float M = -1e30f;
#pragma unroll
            for (int ww = 0; ww < 8; ++ww) { z[ww] = smb[cb][ww][col]; M = fmaxf(M, z[ww].x); }
            float denom = 0.f;
#pragma unroll
            for (int ww = 0; ww < 8; ++ww) denom += z[ww].y * __expf(z[ww].x - M);
            float scale = __expf(mw - M) / denom;
            float cw[4];
#pragma unroll
            for (int j = 0; j < 4; ++j) cw[j] = ex[j] * scale;

#pragma unroll
            for (int m = 0; m < 2; ++m)
#pragma unroll
                for (int q = 0; q < 4; ++q)
#pragma unroll
                    for (int i = 0; i < 4; ++i)
                        s[m][q * 4 + i] = fmaf(cw[m * 2 + (q >> 1)], v[m][q * 4 + i],
                                               s[m][q * 4 + i]);
        }
    }

    // write partial s (bf16), coalesced over pos: part[kc][bd][pos]
    const float mult = (ITER == 0) ? (1.0f / 32.0f) : 1.0f;
#pragma unroll
    for (int m = 0; m < 2; ++m)
#pragma unroll
        for (int q = 0; q < 4; ++q)
#pragma unroll
            for (int i = 0; i < 4; ++i) {
                int bd = bd0 + m * 32 + 8 * q + 4 * h + i;
                part[((size_t)(kc * 512 + bd)) * NP + gpos] = f2bf(s[m][q * 4 + i] * mult);
            }
}

// ---------------- reduce partials + squash ----------------
template<int ITER>
__global__ __launch_bounds__(256) void squash(const unsigned short* __restrict__ part,
                                              float* __restrict__ V,
                                              float* __restrict__ out)
{
    int bid = blockIdx.x;
    int pt = bid >> 2, bg = bid & 3;
    int t = threadIdx.x;
    int pos = pt * 32 + (t & 31);
    int b = bg * 8 + (t >> 5);

    float s[16];
#pragma unroll
    for (int d = 0; d < 16; ++d) s[d] = 0.f;
    for (int kc = 0; kc < KC; ++kc) {
        const unsigned short* pp = part + ((size_t)(kc * 512 + b * 16)) * NP + pos;
#pragma unroll
        for (int d = 0; d < 16; ++d) s[d] += bf2f(pp[(size_t)d * NP]);
    }
    float n2 = 0.f;
#pragma unroll
    for (int d = 0; d < 16; ++d) n2 = fmaf(s[d], s[d], n2);
    float scale = n2 / ((1.0f + n2) * sqrtf(n2 + 1e-8f));

    if constexpr (ITER < 2) {
        float* vp = V + (size_t)pos * 512 + b * 16;
#pragma unroll
        for (int d = 0; d < 16; ++d) {
            float val = s[d] * scale;
            if constexpr (ITER == 0) vp[d] = val;
            else                     vp[d] += val;
        }
    } else {
        if (pos < 900) {
            int batch = pos / 225;
            int opos = pos - batch * 225;
            float* op = out + ((size_t)(batch * 512 + b * 16)) * 225 + opos;
#pragma unroll
            for (int d = 0; d < 16; ++d) op[(size_t)d * 225] = s[d] * scale;
        }
    }
}

// ws layout (bytes):
//   Whi  @ 0          : 4,718,592
//   Wlo  @ 4,718,592  : 4,718,592
//   Phi  @ 9,437,184  : 8,552,448
//   Plo  @ 17,989,632 : 8,552,448
//   part @ 26,542,080 : 17,104,896   (bf16 [18][512][928])
//   V    @ 43,646,976 : 1,900,544    (f32  [928][512])
// total 45.5 MB
extern "C" void kernel_launch(void* const* d_in, const int* in_sizes, int n_in,
                              void* d_out, int out_size, void* d_ws, size_t ws_size,
                              hipStream_t stream)
{
    const float* pose = (const float*)d_in[0];
    const float* Wg   = (const float*)d_in[1];
    float* out = (float*)d_out;
    char* ws = (char*)d_ws;
    unsigned short* Whi  = (unsigned short*)(ws);
    unsigned short* Wlo  = (unsigned short*)(ws + 4718592);
    unsigned short* Phi  = (unsigned short*)(ws + 9437184);
    unsigned short* Plo  = (unsigned short*)(ws + 17989632);
    unsigned short* part = (unsigned short*)(ws + 26542080);
    float* V             = (float*)(ws + 43646976);

    wprep<<<2304, 256, 0, stream>>>(Wg, Whi, Wlo);
    unfold<<<128, 256, 0, stream>>>(pose, Phi, Plo);

    route<0><<<NPT * KC, 512, 0, stream>>>(Whi, Wlo, Phi, Plo, V, part);
    squash<0><<<116, 256, 0, stream>>>(part, V, out);
    route<1><<<NPT * KC, 512, 0, stream>>>(Whi, Wlo, Phi, Plo, V, part);
    squash<1><<<116, 256, 0, stream>>>(part, V, out);
    route<2><<<NPT * KC, 512, 0, stream>>>(Whi, Wlo, Phi, Plo, V, part);
    squash<2><<<116, 256, 0, stream>>>(part, V, out);
}

// Round 12
// 214.495 us; speedup vs baseline: 1.2384x; 1.2384x over previous
//
#include <hip/hip_runtime.h>
#include <math.h>

// ConvCaps: A=B=32, C=D=16, K=3, stride=2, ITERS=3
// pose: [4][512][32][32] f32, W: [288][512][16] f32, out: [4][512][15][15] f32
// pos = batch*225 + oi*15 + oj  (900 valid, padded to 928 = 29 tiles of 32)
#define KC   16      // k-chunks (parallelism axis) — 2 per XCD, pinned
#define KPC  18      // k per chunk (16*18 = 288)
#define NP   928
#define NPT  29

typedef __attribute__((ext_vector_type(8)))  short short8;   // 8 bf16 = 4 VGPR
typedef __attribute__((ext_vector_type(16))) float f32x16;   // MFMA C/D

__device__ __forceinline__ unsigned short f2bf(float x) {
    union { float f; unsigned u; } v; v.f = x;
    unsigned r = v.u + 0x7fffu + ((v.u >> 16) & 1u);
    return (unsigned short)(r >> 16);
}
__device__ __forceinline__ float bf2f(unsigned short h) {
    union { unsigned u; float f; } v; v.u = ((unsigned)h) << 16;
    return v.f;
}

// ---------------- W -> split bf16 (hi, lo) ----------------
__global__ void wprep(const float* __restrict__ W,
                      unsigned short* __restrict__ Whi,
                      unsigned short* __restrict__ Wlo)
{
    int idx = (blockIdx.x * 256 + threadIdx.x) * 4;
    float4 x = *(const float4*)(W + idx);
    ushort4 h, l;
    h.x = f2bf(x.x); l.x = f2bf(x.x - bf2f(h.x));
    h.y = f2bf(x.y); l.y = f2bf(x.y - bf2f(h.y));
    h.z = f2bf(x.z); l.z = f2bf(x.z - bf2f(h.z));
    h.w = f2bf(x.w); l.w = f2bf(x.w - bf2f(h.w));
    *(ushort4*)(Whi + idx) = h;
    *(ushort4*)(Wlo + idx) = l;
}

// ---------------- unfold pose -> split bf16 P[k][pos(928)][c(16)] ----------------
// block = (batch, a); stage 16 pose planes in LDS (row stride 33, plane 1057),
// then emit all 9 kernel-offset copies coalesced.
__global__ __launch_bounds__(256) void unfold(const float* __restrict__ pose,
                                              unsigned short* __restrict__ Phi,
                                              unsigned short* __restrict__ Plo)
{
    __shared__ float lds[16 * 1057];
    const int bid = blockIdx.x;          // 128 = 4 batch * 32 a
    const int batch = bid >> 5;
    const int a = bid & 31;
    const int t = threadIdx.x;

    const float* src = pose + ((size_t)batch * 512 + a * 16) * 1024;
#pragma unroll
    for (int c = 0; c < 16; ++c) {
        float4 v = *(const float4*)(src + c * 1024 + t * 4);
        float* d = &lds[c * 1057 + (t >> 3) * 33 + (t & 7) * 4];
        d[0] = v.x; d[1] = v.y; d[2] = v.z; d[3] = v.w;
    }
    __syncthreads();

    const int c = t & 15;
    const int px = t >> 4;
    for (int it = 0; it < 15; ++it) {
        int pos = it * 16 + px;
        bool ok = pos < 225;
        int pc = ok ? pos : 224;
        int oi = pc / 15, oj = pc - oi * 15;
#pragma unroll
        for (int ki = 0; ki < 3; ++ki)
#pragma unroll
            for (int kj = 0; kj < 3; ++kj) {
                float val = lds[c * 1057 + (oi * 2 + ki) * 33 + (oj * 2 + kj)];
                unsigned short hh = f2bf(val);
                unsigned short ll = f2bf(val - bf2f(hh));
                if (ok) {
                    size_t o = ((size_t)((ki * 3 + kj) * 32 + a) * NP
                                + batch * 225 + pos) * 16 + c;
                    Phi[o] = hh;
                    Plo[o] = ll;
                }
            }
    }
}

// ---------------- routing pass ----------------
// grid = 464 = 8 XCD * 2 kc * 29 pt, block 512 = 8 waves.
// XCD-pinned swizzle (T1 variant): s=bid&7 (XCD via round-robin), j=bid>>3,
// kc = 2s + j/29, pt = j%29 — each 576 KB W chunk is fetched by ONE XCD's L2
// and reused by its 29 pt-blocks (round-10 PMC: W was XCD-duplicated 8x,
// FETCH 65.8 MB @ ~1.1 TB/s fill == the whole dispatch time).
// Swapped MFMA: D[bd(32-tile)][pos(32)] = W_k[bd][c] * p^T[c][pos], 32x32x16 bf16.
//   A frag: row = lane&31 (bd), c = (lane>>5)*8 + j
//   B frag: col = lane&31 (pos), c = (lane>>5)*8 + j
//   C/D  : col = lane&31 (pos), row(bd) = (reg&3) + 8*(reg>>2) + 4*(lane>>5)
// Wave w owns bd in [w*64, w*64+64).  Register-prefetch pipeline over k-steps;
// barrier drains LDS only (global prefetch stays in flight).
template<int ITER>
__global__ __launch_bounds__(512, 2) void route(const unsigned short* __restrict__ Whi,
                                                const unsigned short* __restrict__ Wlo,
                                                const unsigned short* __restrict__ Phi,
                                                const unsigned short* __restrict__ Plo,
                                                const float* __restrict__ V,
                                                unsigned short* __restrict__ part)
{
    __shared__ float2 smb[2][8][32];   // [buf][wave][pos]: (wave max, wave expsum)

    const int bid = blockIdx.x;
    const int s  = bid & 7;            // XCD slot (HW round-robin)
    const int j  = bid >> 3;           // 0..57
    const int kc = s * 2 + (j >= NPT ? 1 : 0);
    const int pt = (j >= NPT) ? (j - NPT) : j;
    const int t = threadIdx.x;
    const int w = t >> 6;
    const int l = t & 63;
    const int col = l & 31;            // pos within tile
    const int h = l >> 5;
    const int gpos = pt * 32 + col;
    const int bd0 = w * 64;

    float vf[2][16];
    if constexpr (ITER > 0) {
        const float* vp = V + (size_t)gpos * 512 + bd0 + 4 * h;
#pragma unroll
        for (int m = 0; m < 2; ++m)
#pragma unroll
            for (int q = 0; q < 4; ++q) {
                float4 x = *(const float4*)(vp + m * 32 + 8 * q);
                vf[m][q * 4 + 0] = x.x; vf[m][q * 4 + 1] = x.y;
                vf[m][q * 4 + 2] = x.z; vf[m][q * 4 + 3] = x.w;
            }
    }

    f32x16 s_acc[2];
#pragma unroll
    for (int m = 0; m < 2; ++m)
#pragma unroll
        for (int r = 0; r < 16; ++r) s_acc[m][r] = 0.f;

    // per-wave fragment stream pointers (k0 = kc*KPC)
    const size_t k0 = (size_t)kc * KPC;
    const unsigned short* pWh = Whi + (k0 * 512 + bd0 + col) * 16 + 8 * h;
    const unsigned short* pWl = Wlo + (k0 * 512 + bd0 + col) * 16 + 8 * h;
    const unsigned short* pPh = Phi + (k0 * NP + gpos) * 16 + 8 * h;
    const unsigned short* pPl = Plo + (k0 * NP + gpos) * 16 + 8 * h;

    short8 ah0 = *(const short8*)(pWh);
    short8 ah1 = *(const short8*)(pWh + 512);
    short8 al0 = *(const short8*)(pWl);
    short8 al1 = *(const short8*)(pWl + 512);
    short8 bh  = *(const short8*)(pPh);
    short8 bl  = *(const short8*)(pPl);

    for (int kl = 0; kl < KPC; ++kl) {
        // prefetch next step's frags (last step reads one k past — lands in the
        // adjacent ws region (Whi->Wlo->Phi->Plo->part), in-bounds, discarded)
        const int nw = (kl + 1) * 8192;      // 512*16 shorts per k
        const int np = (kl + 1) * 14848;     // NP*16 shorts per k
        short8 nah0 = *(const short8*)(pWh + nw);
        short8 nah1 = *(const short8*)(pWh + nw + 512);
        short8 nal0 = *(const short8*)(pWl + nw);
        short8 nal1 = *(const short8*)(pWl + nw + 512);
        short8 nbh  = *(const short8*)(pPh + np);
        short8 nbl  = *(const short8*)(pPl + np);

        if constexpr (ITER == 0) {
            s_acc[0] = __builtin_amdgcn_mfma_f32_32x32x16_bf16(ah0, bh, s_acc[0], 0, 0, 0);
            s_acc[1] = __builtin_amdgcn_mfma_f32_32x32x16_bf16(ah1, bh, s_acc[1], 0, 0, 0);
            s_acc[0] = __builtin_amdgcn_mfma_f32_32x32x16_bf16(ah0, bl, s_acc[0], 0, 0, 0);
            s_acc[1] = __builtin_amdgcn_mfma_f32_32x32x16_bf16(ah1, bl, s_acc[1], 0, 0, 0);
            s_acc[0] = __builtin_amdgcn_mfma_f32_32x32x16_bf16(al0, bh, s_acc[0], 0, 0, 0);
            s_acc[1] = __builtin_amdgcn_mfma_f32_32x32x16_bf16(al1, bh, s_acc[1], 0, 0, 0);
        } else {
            f32x16 v[2];
#pragma unroll
            for (int m = 0; m < 2; ++m)
#pragma unroll
                for (int r = 0; r < 16; ++r) v[m][r] = 0.f;
            v[0] = __builtin_amdgcn_mfma_f32_32x32x16_bf16(ah0, bh, v[0], 0, 0, 0);
            v[1] = __builtin_amdgcn_mfma_f32_32x32x16_bf16(ah1, bh, v[1], 0, 0, 0);
            v[0] = __builtin_amdgcn_mfma_f32_32x32x16_bf16(ah0, bl, v[0], 0, 0, 0);
            v[1] = __builtin_amdgcn_mfma_f32_32x32x16_bf16(ah1, bl, v[1], 0, 0, 0);
            v[0] = __builtin_amdgcn_mfma_f32_32x32x16_bf16(al0, bh, v[0], 0, 0, 0);
            v[1] = __builtin_amdgcn_mfma_f32_32x32x16_bf16(al1, bh, v[1], 0, 0, 0);

            // logits[pos, b] = votes . V ;  b = w*4 + (m*2 + (q>>1))
            float lp[4] = {0.f, 0.f, 0.f, 0.f};
#pragma unroll
            for (int m = 0; m < 2; ++m)
#pragma unroll
                for (int q = 0; q < 4; ++q)
#pragma unroll
                    for (int i = 0; i < 4; ++i)
                        lp[m * 2 + (q >> 1)] = fmaf(v[m][q * 4 + i], vf[m][q * 4 + i],
                                                    lp[m * 2 + (q >> 1)]);
#pragma unroll
            for (int j2 = 0; j2 < 4; ++j2) lp[j2] += __shfl_xor(lp[j2], 32);

            // wave-local softmax partial over this wave's 4 b's
            float mw = fmaxf(fmaxf(lp[0], lp[1]), fmaxf(lp[2], lp[3]));
            float ex[4], sw = 0.f;
#pragma unroll
            for (int j2 = 0; j2 < 4; ++j2) { ex[j2] = __expf(lp[j2] - mw); sw += ex[j2]; }
            if (h == 0) smb[kl & 1][w][col] = make_float2(mw, sw);
            // LDS-only drain + barrier: global prefetch stays in flight
            asm volatile("s_waitcnt lgkmcnt(0)\n\ts_barrier" ::: "memory");
            float2 z[8];
            float M = -1e30f;
#pragma unroll
            for (int ww = 0; ww < 8; ++ww) { z[ww] = smb[kl & 1][ww][col]; M = fmaxf(M, z[ww].x); }
            float denom = 0.f;
#pragma unroll
            for (int ww = 0; ww < 8; ++ww) denom += z[ww].y * __expf(z[ww].x - M);
            float scale = __expf(mw - M) / denom;
            float cw[4];
#pragma unroll
            for (int j2 = 0; j2 < 4; ++j2) cw[j2] = ex[j2] * scale;

#pragma unroll
            for (int m = 0; m < 2; ++m)
#pragma unroll
                for (int q = 0; q < 4; ++q)
#pragma unroll
                    for (int i = 0; i < 4; ++i)
                        s_acc[m][q * 4 + i] = fmaf(cw[m * 2 + (q >> 1)], v[m][q * 4 + i],
                                                   s_acc[m][q * 4 + i]);
        }

        ah0 = nah0; ah1 = nah1; al0 = nal0; al1 = nal1; bh = nbh; bl = nbl;
    }

    // write partial s (bf16), coalesced over pos: part[kc][bd][pos]
    const float mult = (ITER == 0) ? (1.0f / 32.0f) : 1.0f;
#pragma unroll
    for (int m = 0; m < 2; ++m)
#pragma unroll
        for (int q = 0; q < 4; ++q)
#pragma unroll
            for (int i = 0; i < 4; ++i) {
                int bd = bd0 + m * 32 + 8 * q + 4 * h + i;
                part[((size_t)(kc * 512 + bd)) * NP + gpos] = f2bf(s_acc[m][q * 4 + i] * mult);
            }
}

// ---------------- reduce partials + squash ----------------
template<int ITER>
__global__ __launch_bounds__(256) void squash(const unsigned short* __restrict__ part,
                                              float* __restrict__ V,
                                              float* __restrict__ out)
{
    int bid = blockIdx.x;
    int pt = bid >> 2, bg = bid & 3;
    int t = threadIdx.x;
    int pos = pt * 32 + (t & 31);
    int b = bg * 8 + (t >> 5);

    float s[16];
#pragma unroll
    for (int d = 0; d < 16; ++d) s[d] = 0.f;
    for (int kc = 0; kc < KC; ++kc) {
        const unsigned short* pp = part + ((size_t)(kc * 512 + b * 16)) * NP + pos;
#pragma unroll
        for (int d = 0; d < 16; ++d) s[d] += bf2f(pp[(size_t)d * NP]);
    }
    float n2 = 0.f;
#pragma unroll
    for (int d = 0; d < 16; ++d) n2 = fmaf(s[d], s[d], n2);
    float scale = n2 / ((1.0f + n2) * sqrtf(n2 + 1e-8f));

    if constexpr (ITER < 2) {
        float* vp = V + (size_t)pos * 512 + b * 16;
#pragma unroll
        for (int d = 0; d < 16; ++d) {
            float val = s[d] * scale;
            if constexpr (ITER == 0) vp[d] = val;
            else                     vp[d] += val;
        }
    } else {
        if (pos < 900) {
            int batch = pos / 225;
            int opos = pos - batch * 225;
            float* op = out + ((size_t)(batch * 512 + b * 16)) * 225 + opos;
#pragma unroll
            for (int d = 0; d < 16; ++d) op[(size_t)d * 225] = s[d] * scale;
        }
    }
}

// ws layout (bytes):
//   Whi  @ 0          : 4,718,592
//   Wlo  @ 4,718,592  : 4,718,592
//   Phi  @ 9,437,184  : 8,552,448
//   Plo  @ 17,989,632 : 8,552,448
//   part @ 26,542,080 : 15,204,352   (bf16 [16][512][928])
//   V    @ 41,746,432 : 1,900,544    (f32  [928][512])
// total 43.6 MB
extern "C" void kernel_launch(void* const* d_in, const int* in_sizes, int n_in,
                              void* d_out, int out_size, void* d_ws, size_t ws_size,
                              hipStream_t stream)
{
    const float* pose = (const float*)d_in[0];
    const float* Wg   = (const float*)d_in[1];
    float* out = (float*)d_out;
    char* ws = (char*)d_ws;
    unsigned short* Whi  = (unsigned short*)(ws);
    unsigned short* Wlo  = (unsigned short*)(ws + 4718592);
    unsigned short* Phi  = (unsigned short*)(ws + 9437184);
    unsigned short* Plo  = (unsigned short*)(ws + 17989632);
    unsigned short* part = (unsigned short*)(ws + 26542080);
    float* V             = (float*)(ws + 41746432);

    wprep<<<2304, 256, 0, stream>>>(Wg, Whi, Wlo);
    unfold<<<128, 256, 0, stream>>>(pose, Phi, Plo);

    route<0><<<8 * 2 * NPT, 512, 0, stream>>>(Whi, Wlo, Phi, Plo, V, part);
    squash<0><<<116, 256, 0, stream>>>(part, V, out);
    route<1><<<8 * 2 * NPT, 512, 0, stream>>>(Whi, Wlo, Phi, Plo, V, part);
    squash<1><<<116, 256, 0, stream>>>(part, V, out);
    route<2><<<8 * 2 * NPT, 512, 0, stream>>>(Whi, Wlo, Phi, Plo, V, part);
    squash<2><<<116, 256, 0, stream>>>(part, V, out);
}